// Round 6
// baseline (270.675 us; speedup 1.0000x reference)
//
#include <hip/hip_runtime.h>

// FieldAwareFMLayer: x (bs, 40, 39, 16) fp32.
// out[n] = sum_{0<=i<=j<=38} dot(x[n,i,j,:], x[n,j+1,i,:])
//
// 204.5 MB exactly-once read => HBM-bound, floor ~30-33 us (less if L3-hit).
// R3 fixed the MLP/latency bound (14 batched float4 loads/thread).
// R4 removed memory-dependent addressing (pure-VALU triangular decode).
// R5 (contiguous HBM via LDS staging) was NEUTRAL -> DRAM pattern not the
// limiter; reverted to the no-LDS R4 structure.
// R6: drop __builtin_nontemporal_load. The input fits in the 256 MB
// Infinity Cache and is freshly restored by the harness d2d copy right
// before this kernel runs; the nt hint discourages cache retention and can
// defeat those L3 hits. Plain loads let the read stream hit L3 at >HBM BW.

#define NF 40
#define NC 39
#define ED 16
#define NPAIRS 780
#define ROW_FLOATS (NF * NC * ED)     // 24960 floats per batch row
#define NTASKS (NPAIRS * 4)           // one float4 partial-dot per task = 3120
#define NTH 512
#define TRIPS ((NTASKS + NTH - 1) / NTH)   // 7

typedef float f32x4 __attribute__((ext_vector_type(4)));

__global__ __launch_bounds__(NTH) void ffm_interact_kernel(
        const float* __restrict__ x, float* __restrict__ out) {
    const int n = blockIdx.x;
    const int tid = threadIdx.x;
    const int q = tid & 3;            // quad within embedding
    const int p0 = tid >> 2;          // p_k = p0 + 128*k
    const f32x4* __restrict__ base4 =
        (const f32x4*)(x + (size_t)n * ROW_FLOATS);

    // 1) pure-VALU index decode (no memory dependency):
    //    pair p -> (i,j): i = floor((79 - sqrt(6241 - 8p))/2), guarded;
    //    S(i) = 39i - i(i-1)/2; j = i + p - S(i).
    int aoff[TRIPS], boff[TRIPS];
    #pragma unroll
    for (int k = 0; k < TRIPS; ++k) {
        int p = p0 + 128 * k;
        p = p < NPAIRS ? p : (NPAIRS - 1);       // clamp tail (masked below)
        const float disc = 6241.0f - 8.0f * (float)p;
        int i = (int)((79.0f - __builtin_sqrtf(disc)) * 0.5f);
        int Si = 39 * i - ((i * (i - 1)) >> 1);
        if (p < Si) { --i; Si = 39 * i - ((i * (i - 1)) >> 1); }
        else { const int Si1 = Si + (NC - i); if (p >= Si1) { ++i; Si = Si1; } }
        const int j = i + (p - Si);
        aoff[k] = (i * NC + j) * 4 + q;          // a = (i, j)
        boff[k] = ((j + 1) * NC + i) * 4 + q;    // b = (j+1, i)
    }

    // 2) all global loads batched -> 14 outstanding 16B loads per thread,
    //    plain loads (L3-allocating) since input is likely Infinity-Cache
    //    resident from the harness restore copy.
    f32x4 av[TRIPS], bv[TRIPS];
    #pragma unroll
    for (int k = 0; k < TRIPS; ++k)
        av[k] = base4[aoff[k]];
    #pragma unroll
    for (int k = 0; k < TRIPS; ++k)
        bv[k] = base4[boff[k]];

    // 3) FMAs, tail-masked
    float acc = 0.0f;
    #pragma unroll
    for (int k = 0; k < TRIPS; ++k) {
        const float m = ((tid + k * NTH) < NTASKS) ? 1.0f : 0.0f;
        acc = fmaf(m * av[k][0], bv[k][0], acc);
        acc = fmaf(m * av[k][1], bv[k][1], acc);
        acc = fmaf(m * av[k][2], bv[k][2], acc);
        acc = fmaf(m * av[k][3], bv[k][3], acc);
    }

    // wave-64 reduce, then cross-wave via LDS
    #pragma unroll
    for (int off = 32; off > 0; off >>= 1)
        acc += __shfl_down(acc, off, 64);

    __shared__ float wave_sum[NTH / 64];
    if ((tid & 63) == 0) wave_sum[tid >> 6] = acc;
    __syncthreads();
    if (tid == 0) {
        float s = 0.0f;
        #pragma unroll
        for (int w = 0; w < NTH / 64; ++w) s += wave_sum[w];
        out[n] = s;
    }
}

extern "C" void kernel_launch(void* const* d_in, const int* in_sizes, int n_in,
                              void* d_out, int out_size, void* d_ws, size_t ws_size,
                              hipStream_t stream) {
    const float* x = (const float*)d_in[0];
    float* out = (float*)d_out;
    const int bs = in_sizes[0] / ROW_FLOATS;   // 2048
    ffm_interact_kernel<<<bs, NTH, 0, stream>>>(x, out);
}

// Round 7
// 261.461 us; speedup vs baseline: 1.0352x; 1.0352x over previous
//
#include <hip/hip_runtime.h>

// FieldAwareFMLayer: x (bs, 40, 39, 16) fp32.
// out[n] = sum_{0<=i<=j<=38} dot(x[n,i,j,:], x[n,j+1,i,:])
//
// 204.5 MB exactly-once read => memory-bound; fixed harness traffic
// (poison fill + input restore) dominates the benched dur_us.
// Experiment history:
//   R3 WIN  : batch 14 independent float4 loads/thread (MLP/latency fix).
//   R4 ~    : pure-VALU triangular index decode (no memory-dependent addr).
//   R5 NEUT : contiguous HBM via LDS staging -> DRAM pattern not limiter.
//   R6 REGR : dropping nontemporal loads cost +15.7 us -> nt is a real win
//             (exactly-once stream; cache allocation only thrashes).
// R7: R4 structure restored (nt loads), a/b load issue interleaved per pair
// so operand pairs complete together; nt store for out.

#define NF 40
#define NC 39
#define ED 16
#define NPAIRS 780
#define ROW_FLOATS (NF * NC * ED)     // 24960 floats per batch row
#define NTASKS (NPAIRS * 4)           // one float4 partial-dot per task = 3120
#define NTH 512
#define TRIPS ((NTASKS + NTH - 1) / NTH)   // 7

typedef float f32x4 __attribute__((ext_vector_type(4)));

__global__ __launch_bounds__(NTH) void ffm_interact_kernel(
        const float* __restrict__ x, float* __restrict__ out) {
    const int n = blockIdx.x;
    const int tid = threadIdx.x;
    const int q = tid & 3;            // quad within embedding
    const int p0 = tid >> 2;          // p_k = p0 + 128*k
    const f32x4* __restrict__ base4 =
        (const f32x4*)(x + (size_t)n * ROW_FLOATS);

    // 1) pure-VALU index decode (no memory dependency):
    //    pair p -> (i,j): i = floor((79 - sqrt(6241 - 8p))/2), guarded;
    //    S(i) = 39i - i(i-1)/2; j = i + p - S(i).
    int aoff[TRIPS], boff[TRIPS];
    #pragma unroll
    for (int k = 0; k < TRIPS; ++k) {
        int p = p0 + 128 * k;
        p = p < NPAIRS ? p : (NPAIRS - 1);       // clamp tail (masked below)
        const float disc = 6241.0f - 8.0f * (float)p;
        int i = (int)((79.0f - __builtin_sqrtf(disc)) * 0.5f);
        int Si = 39 * i - ((i * (i - 1)) >> 1);
        if (p < Si) { --i; Si = 39 * i - ((i * (i - 1)) >> 1); }
        else { const int Si1 = Si + (NC - i); if (p >= Si1) { ++i; Si = Si1; } }
        const int j = i + (p - Si);
        aoff[k] = (i * NC + j) * 4 + q;          // a = (i, j)
        boff[k] = ((j + 1) * NC + i) * 4 + q;    // b = (j+1, i)
    }

    // 2) all global loads batched, nontemporal (exactly-once stream),
    //    interleaved a/b so each FMA pair's operands retire together.
    f32x4 av[TRIPS], bv[TRIPS];
    #pragma unroll
    for (int k = 0; k < TRIPS; ++k) {
        av[k] = __builtin_nontemporal_load(&base4[aoff[k]]);
        bv[k] = __builtin_nontemporal_load(&base4[boff[k]]);
    }

    // 3) FMAs, tail-masked
    float acc = 0.0f;
    #pragma unroll
    for (int k = 0; k < TRIPS; ++k) {
        const float m = ((tid + k * NTH) < NTASKS) ? 1.0f : 0.0f;
        acc = fmaf(m * av[k][0], bv[k][0], acc);
        acc = fmaf(m * av[k][1], bv[k][1], acc);
        acc = fmaf(m * av[k][2], bv[k][2], acc);
        acc = fmaf(m * av[k][3], bv[k][3], acc);
    }

    // wave-64 reduce, then cross-wave via LDS
    #pragma unroll
    for (int off = 32; off > 0; off >>= 1)
        acc += __shfl_down(acc, off, 64);

    __shared__ float wave_sum[NTH / 64];
    if ((tid & 63) == 0) wave_sum[tid >> 6] = acc;
    __syncthreads();
    if (tid == 0) {
        float s = 0.0f;
        #pragma unroll
        for (int w = 0; w < NTH / 64; ++w) s += wave_sum[w];
        __builtin_nontemporal_store(s, &out[n]);
    }
}

extern "C" void kernel_launch(void* const* d_in, const int* in_sizes, int n_in,
                              void* d_out, int out_size, void* d_ws, size_t ws_size,
                              hipStream_t stream) {
    const float* x = (const float*)d_in[0];
    float* out = (float*)d_out;
    const int bs = in_sizes[0] / ROW_FLOATS;   // 2048
    ffm_interact_kernel<<<bs, NTH, 0, stream>>>(x, out);
}

// Round 8
// 256.569 us; speedup vs baseline: 1.0550x; 1.0191x over previous
//
#include <hip/hip_runtime.h>

// FieldAwareFMLayer: x (bs, 40, 39, 16) fp32.
// out[n] = sum_{0<=i<=j<=38} dot(x[n,i,j,:], x[n,j+1,i,:])
//
// 204.5 MB exactly-once read => memory-bound. Benched dur_us is dominated
// by fixed harness traffic (818 MB poison fill + 409 MB input restore
// ~181 us); kernel itself ~35-45 us vs ~33 us streaming floor.
// Experiment ledger:
//   R3 WIN  : batch 14 independent float4 loads/thread (MLP/latency fix).
//   R4 BEST : + pure-VALU triangular decode, grouped a-then-b nt loads
//             -> 254.9 us.
//   R5 NEUT : fully-contiguous HBM via LDS staging -> pattern not limiter.
//   R6 REGR : cache-allocating loads +15.7 us -> nt hint is load-bearing.
//   R7 REGR : interleaved a/b issue +6.5 us -> grouped issue load-bearing.
// R8 = exact R4 (the best-known configuration).

#define NF 40
#define NC 39
#define ED 16
#define NPAIRS 780
#define ROW_FLOATS (NF * NC * ED)     // 24960 floats per batch row
#define NTASKS (NPAIRS * 4)           // one float4 partial-dot per task = 3120
#define NTH 512
#define TRIPS ((NTASKS + NTH - 1) / NTH)   // 7

typedef float f32x4 __attribute__((ext_vector_type(4)));

__global__ __launch_bounds__(NTH) void ffm_interact_kernel(
        const float* __restrict__ x, float* __restrict__ out) {
    const int n = blockIdx.x;
    const int tid = threadIdx.x;
    const int q = tid & 3;            // quad within embedding
    const int p0 = tid >> 2;          // p_k = p0 + 128*k
    const f32x4* __restrict__ base4 =
        (const f32x4*)(x + (size_t)n * ROW_FLOATS);

    // 1) pure-VALU index decode (no memory dependency):
    //    pair p -> (i,j): i = floor((79 - sqrt(6241 - 8p))/2), guarded;
    //    S(i) = 39i - i(i-1)/2; j = i + p - S(i).
    int aoff[TRIPS], boff[TRIPS];
    #pragma unroll
    for (int k = 0; k < TRIPS; ++k) {
        int p = p0 + 128 * k;
        p = p < NPAIRS ? p : (NPAIRS - 1);       // clamp tail (masked below)
        const float disc = 6241.0f - 8.0f * (float)p;
        int i = (int)((79.0f - __builtin_sqrtf(disc)) * 0.5f);
        int Si = 39 * i - ((i * (i - 1)) >> 1);
        if (p < Si) { --i; Si = 39 * i - ((i * (i - 1)) >> 1); }
        else { const int Si1 = Si + (NC - i); if (p >= Si1) { ++i; Si = Si1; } }
        const int j = i + (p - Si);
        aoff[k] = (i * NC + j) * 4 + q;          // a = (i, j)
        boff[k] = ((j + 1) * NC + i) * 4 + q;    // b = (j+1, i)
    }

    // 2) all global loads batched -> 14 outstanding 16B nt loads per thread,
    //    grouped: all a-side, then all b-side (grouped issue is load-bearing).
    f32x4 av[TRIPS], bv[TRIPS];
    #pragma unroll
    for (int k = 0; k < TRIPS; ++k)
        av[k] = __builtin_nontemporal_load(&base4[aoff[k]]);
    #pragma unroll
    for (int k = 0; k < TRIPS; ++k)
        bv[k] = __builtin_nontemporal_load(&base4[boff[k]]);

    // 3) FMAs, tail-masked
    float acc = 0.0f;
    #pragma unroll
    for (int k = 0; k < TRIPS; ++k) {
        const float m = ((tid + k * NTH) < NTASKS) ? 1.0f : 0.0f;
        acc = fmaf(m * av[k][0], bv[k][0], acc);
        acc = fmaf(m * av[k][1], bv[k][1], acc);
        acc = fmaf(m * av[k][2], bv[k][2], acc);
        acc = fmaf(m * av[k][3], bv[k][3], acc);
    }

    // wave-64 reduce, then cross-wave via LDS
    #pragma unroll
    for (int off = 32; off > 0; off >>= 1)
        acc += __shfl_down(acc, off, 64);

    __shared__ float wave_sum[NTH / 64];
    if ((tid & 63) == 0) wave_sum[tid >> 6] = acc;
    __syncthreads();
    if (tid == 0) {
        float s = 0.0f;
        #pragma unroll
        for (int w = 0; w < NTH / 64; ++w) s += wave_sum[w];
        out[n] = s;
    }
}

extern "C" void kernel_launch(void* const* d_in, const int* in_sizes, int n_in,
                              void* d_out, int out_size, void* d_ws, size_t ws_size,
                              hipStream_t stream) {
    const float* x = (const float*)d_in[0];
    float* out = (float*)d_out;
    const int bs = in_sizes[0] / ROW_FLOATS;   // 2048
    ffm_interact_kernel<<<bs, NTH, 0, stream>>>(x, out);
}